// Round 3
// baseline (147.491 us; speedup 1.0000x reference)
//
#include <hip/hip_runtime.h>
#include <hip/hip_bf16.h>

#define NB 8
#define CH 384
#define SL 1024
#define NH 6
#define HD 64
#define WIN 4
#define LOG2E 1.44269504088896340736f
#define SCALE 0.125f            // 1/sqrt(64)
#define QSCALE (SCALE * LOG2E)  // fold log2(e): attention runs in exp2 domain
#define SCLAMP2 14.4269504f     // 10*log2e; exp2(14.43)=e^10=22026 < fp16 max
// LDS tile pad: 76 f16 = 38 dwords = 6 mod 32 banks. 72 (=36 dw = 4 mod 32)
// gave 4-way bank aliasing on 16-row fragment reads (4.1M conflict cycles in
// attn, 1.06M in qkv). 38 mod 32 = 6: lid*6 mod 32 is injective over 16 lids,
// quad offset +4 adds only 2-way aliasing (free per m136).
#define PAD 76

typedef _Float16 f16;
typedef f16   f16x8 __attribute__((ext_vector_type(8)));
typedef f16   f16x4 __attribute__((ext_vector_type(4)));
typedef float f32x4 __attribute__((ext_vector_type(4)));
typedef unsigned short u16x8 __attribute__((ext_vector_type(8)));
typedef unsigned short u16x4 __attribute__((ext_vector_type(4)));

static __device__ __forceinline__ unsigned short f2bf_rne(float f) {
  unsigned int u = __float_as_uint(f);
  unsigned int r = (u + 0x7fffu + ((u >> 16) & 1u)) >> 16;
  return (unsigned short)r;
}
static __device__ __forceinline__ float bfb(unsigned short u) {   // bf16 bits -> f32
  return __uint_as_float((unsigned int)u << 16);
}
static __device__ __forceinline__ float ldbf(const void* p, size_t i) {
  return bfb(((const unsigned short*)p)[i]);
}
static __device__ __forceinline__ float ldf(const void* p, size_t i) {
  return ((const float*)p)[i];
}
// raw v_exp_f32 (2^x); safe: upstream clamps the high side, low side flushes to 0
static __device__ __forceinline__ float fexp2(float x) {
  return __builtin_amdgcn_exp2f(x);
}

// ---------------------------------------------------------------------------
// Kc: merged conversions + inline dtype probe. (unchanged this round — its
// LDS tile keeps pad 72; not measured hot, don't touch unmeasured code)
// ---------------------------------------------------------------------------
__global__ __launch_bounds__(256) void cvt_k(
    const void* __restrict__ w0, const void* __restrict__ w1,
    const void* __restrict__ w2, const void* __restrict__ w3,
    const void* __restrict__ b0, const void* __restrict__ b1,
    const void* __restrict__ b2, const void* __restrict__ b3,
    const void* __restrict__ x,
    f16* __restrict__ wh, float* __restrict__ bh, f16* __restrict__ xt,
    int* __restrict__ flag)
{
  __shared__ f16 lt_[64][72];
  __shared__ int sflag;
  const int bx = blockIdx.x, t = threadIdx.x;

  // inline probe: wave 0 samples 256 values of x, checks bf16-exponent range
  {
    int cnt = 0;
    if (t < 64) {
      const unsigned int* xu = (const unsigned int*)x;
#pragma unroll
      for (int i = 0; i < 4; ++i) {
        unsigned int e = (xu[t * 4 + i] >> 7) & 0xFF;
        if (e >= 110 && e <= 140) ++cnt;
      }
#pragma unroll
      for (int s = 1; s < 64; s <<= 1) cnt += __shfl_xor(cnt, s);
      if (t == 0) sflag = (cnt >= 128) ? 1 : 0;
    }
    __syncthreads();
  }
  const int isbf = sflag;

  if (bx < 576) {                       // 144 blocks per matrix
    int g = bx / 144;
    const void* src = (g == 0) ? w0 : (g == 1) ? w1 : (g == 2) ? w2 : w3;
    size_t idx = (size_t)(bx % 144) * 1024 + t * 4;
    f16* dst = wh + (size_t)g * CH * CH + idx;
    f16x4 o;
    if (!isbf) {
      float4 v = *(const float4*)((const float*)src + idx);
      o[0] = (f16)v.x; o[1] = (f16)v.y; o[2] = (f16)v.z; o[3] = (f16)v.w;
    } else {
      u16x4 v = *(const u16x4*)((const unsigned short*)src + idx);
#pragma unroll
      for (int j = 0; j < 4; ++j) o[j] = (f16)bfb(v[j]);
    }
    *(f16x4*)dst = o;
    return;
  }
  if (bx == 576) {                      // biases + publish flag
    if (t == 0) *flag = isbf;
    for (int e = t; e < 4 * CH; e += 256) {
      int g = e / CH, i = e - g * CH;
      const void* src = (g == 0) ? b0 : (g == 1) ? b1 : (g == 2) ? b2 : b3;
      bh[e] = isbf ? ldbf(src, i) : ldf(src, i);
    }
    return;
  }
  // x transpose: e in 0..767
  const int e  = bx - 577;
  const int l0 = (e & 15) * 64;
  const int c0 = ((e >> 4) % 6) * 64;
  const int b  = e / 96;
  const int row = t >> 4, lseg = t & 15;

  if (!isbf) {
    const float* xf = (const float*)x;
#pragma unroll
    for (int k = 0; k < 4; ++k) {
      int c = c0 + row + 16 * k;
      float4 v = *(const float4*)&xf[((size_t)b * CH + c) * SL + l0 + lseg * 4];
      lt_[lseg * 4 + 0][row + 16 * k] = (f16)v.x;
      lt_[lseg * 4 + 1][row + 16 * k] = (f16)v.y;
      lt_[lseg * 4 + 2][row + 16 * k] = (f16)v.z;
      lt_[lseg * 4 + 3][row + 16 * k] = (f16)v.w;
    }
  } else {
    const unsigned short* xu = (const unsigned short*)x;
#pragma unroll
    for (int k = 0; k < 4; ++k) {
      int c = c0 + row + 16 * k;
      u16x4 v = *(const u16x4*)&xu[((size_t)b * CH + c) * SL + l0 + lseg * 4];
#pragma unroll
      for (int j = 0; j < 4; ++j)
        lt_[lseg * 4 + j][row + 16 * k] = (f16)bfb(v[j]);
    }
  }
  __syncthreads();
  const int l = t >> 2, seg = t & 3;
  f16* dst = &xt[((size_t)b * SL + l0 + l) * CH + c0 + seg * 16];
  *(f16x8*)dst       = *(const f16x8*)&lt_[l][seg * 16];
  *(f16x8*)(dst + 8) = *(const f16x8*)&lt_[l][seg * 16 + 8];
}

// ---------------------------------------------------------------------------
// K1: QKV projection, 128x128-tile fp16 MFMA GEMM.
// round-14: LDS pad 72 -> 76 (bank-conflict fix, see PAD comment).
// ---------------------------------------------------------------------------
__global__ __launch_bounds__(256) void qkv_k(
    const f16* __restrict__ wh, const float* __restrict__ bh, const f16* __restrict__ xt,
    f16* __restrict__ Q, f16* __restrict__ K, f16* __restrict__ Vt)
{
  __shared__ f16 sm[2][128][PAD];       // sA = sm[0], sB = sm[1]

  const int t   = threadIdx.x;
  const int l0  = blockIdx.x * 128;
  const int mty = blockIdx.y;           // 0..8
  const int b   = blockIdx.z;
  const int wid = t >> 6, lane = t & 63;
  const int quad = lane >> 4, lid = lane & 15;
  const int rw = wid >> 1, cw = wid & 1;

  const int g0   = mty / 3;             // 0=Q, 1=K, 2=V
  const int m128 = (mty % 3) * 128;
  const f16* wg  = wh + (size_t)g0 * CH * CH;

  f32x4 acc[4][4];
#pragma unroll
  for (int mt = 0; mt < 4; ++mt)
#pragma unroll
    for (int nt = 0; nt < 4; ++nt) acc[mt][nt] = (f32x4){0.f, 0.f, 0.f, 0.f};

  for (int c0 = 0; c0 < CH; c0 += 64) {
    __syncthreads();
#pragma unroll
    for (int k = 0; k < 4; ++k) {
      int cidx = t + k * 256;
      int r = cidx >> 3, c8 = (cidx & 7) * 8;
      *(f16x8*)&sm[0][r][c8] = *(const f16x8*)&wg[(size_t)(m128 + r) * CH + c0 + c8];
      *(f16x8*)&sm[1][r][c8] = *(const f16x8*)&xt[((size_t)b * SL + l0 + r) * CH + c0 + c8];
    }
    __syncthreads();
#pragma unroll
    for (int kk = 0; kk < 2; ++kk) {
      f16x8 bf[4];
#pragma unroll
      for (int nt = 0; nt < 4; ++nt)
        bf[nt] = *(const f16x8*)&sm[1][cw * 64 + nt * 16 + lid][kk * 32 + quad * 8];
#pragma unroll
      for (int mt = 0; mt < 4; ++mt) {
        f16x8 af = *(const f16x8*)&sm[0][rw * 64 + mt * 16 + lid][kk * 32 + quad * 8];
#pragma unroll
        for (int nt = 0; nt < 4; ++nt)
          acc[mt][nt] = __builtin_amdgcn_mfma_f32_16x16x32_f16(af, bf[nt], acc[mt][nt], 0, 0, 0);
      }
    }
  }
  __syncthreads();                      // protect LDS overlay

  const int h = (mty % 3) * 2 + rw;
  float bias[4][4];
#pragma unroll
  for (int mt = 0; mt < 4; ++mt)
#pragma unroll
    for (int r = 0; r < 4; ++r)
      bias[mt][r] = bh[g0 * CH + m128 + rw * 64 + mt * 16 + quad * 4 + r];
  const float osc = (g0 == 0) ? QSCALE : 1.0f;

  f16 (*lo4)[64][PAD] = (f16(*)[64][PAD])sm;   // wave-private overlay

  if (g0 < 2) {                         // Q or K: lo[l][d], store (B,H,L,64)
#pragma unroll
    for (int mt = 0; mt < 4; ++mt)
#pragma unroll
      for (int nt = 0; nt < 4; ++nt) {
        f16x4 vv;
#pragma unroll
        for (int r = 0; r < 4; ++r)
          vv[r] = (f16)((acc[mt][nt][r] + bias[mt][r]) * osc);
        *(f16x4*)&lo4[wid][nt * 16 + lid][mt * 16 + quad * 4] = vv;
      }
    __builtin_amdgcn_s_waitcnt(0);
    f16* base = ((g0 == 0) ? Q : K) + ((size_t)(b * NH + h) * SL + l0 + cw * 64) * HD;
#pragma unroll
    for (int p = 0; p < 8; ++p) {
      int lr = p * 8 + (lane >> 3), seg = lane & 7;
      *(f16x8*)&base[(size_t)lr * HD + seg * 8] = *(const f16x8*)&lo4[wid][lr][seg * 8];
    }
  } else {                              // V: lo[d][l], store (B,H,64,L)
#pragma unroll
    for (int mt = 0; mt < 4; ++mt)
#pragma unroll
      for (int nt = 0; nt < 4; ++nt)
#pragma unroll
        for (int r = 0; r < 4; ++r)
          lo4[wid][mt * 16 + quad * 4 + r][nt * 16 + lid] =
            (f16)(acc[mt][nt][r] + bias[mt][r]);
    __builtin_amdgcn_s_waitcnt(0);
    f16* base = Vt + ((size_t)(b * NH + h) * HD) * SL + l0 + cw * 64;
#pragma unroll
    for (int p = 0; p < 8; ++p) {
      int dr = p * 8 + (lane >> 3), seg = lane & 7;
      *(f16x8*)&base[(size_t)dr * SL + seg * 8] = *(const f16x8*)&lo4[wid][dr][seg * 8];
    }
  }
}

// ---------------------------------------------------------------------------
// K2: MFMA flash attention, single-barrier double-buffered K-loop.
// round-14: bufk/bufv pad 72 -> 76 (bank-conflict fix; LDS 46.5 KB, still
// 3 blocks/CU). Everything else identical to round-13.
// ---------------------------------------------------------------------------
__global__ __launch_bounds__(256) void attn_k(
    const f16* __restrict__ Qs, const f16* __restrict__ Kg, const f16* __restrict__ Vtg,
    const void* __restrict__ embk, const void* __restrict__ embv,
    f16* __restrict__ R2t, const int* __restrict__ flag)
{
  __shared__ f16 bufk[2][64][PAD];
  __shared__ f16 bufv[2][64][PAD];      // col-permuted V^T
  __shared__ float lbias[64][12];
  __shared__ float lsb[64][12];
  __shared__ float lev[9][64];
  __shared__ float ll64[64];

  const int isbf = *flag;
  const int t    = threadIdx.x;

  const int id   = blockIdx.x;
  const int xcd  = id & 7;
  const int kk   = id >> 3;
  const int pair = (kk % 6) * 8 + xcd;
  const int i0   = (kk / 6) * 64;
  const int b    = pair / NH;
  const int h    = pair % NH;

  const int wid  = t >> 6;
  const int lane = t & 63;
  const int quad = lane >> 4;
  const int lid  = lane & 15;

  const f16* Qb = Qs  + ((size_t)(b * NH + h) * SL) * HD;
  const f16* Kb = Kg  + ((size_t)(b * NH + h) * SL) * HD;
  const f16* Vb = Vtg + ((size_t)(b * NH + h) * HD) * SL;

  f16 (* const lq)[PAD] = bufk[0];      // prologue overlay
  f16 (* const lo)[PAD] = bufk[0];      // epilogue overlay

  const int r_0 = t >> 3,         c8 = (t & 7) * 8;
  const int r_1 = (t + 256) >> 3;
  const int u0   = t & 7;
  const int jt0  = u0 >> 1;
  const int colA = ((2 * u0) & 3) * 16 + jt0 * 4;
  const int colB = ((2 * u0 + 1) & 3) * 16 + jt0 * 4;

  // stage Q tile into bufk[0]
#pragma unroll
  for (int k = 0; k < 2; ++k) {
    int c = t + k * 256, r = c >> 3, cc8 = (c & 7) * 8;
    *(f16x8*)&lq[r][cc8] = *(const f16x8*)&Qb[(size_t)(i0 + r) * HD + cc8];
  }
  // prefetch tile 0 into registers
  f16x8 pk0 = *(const f16x8*)&Kb[(size_t)r_0 * HD + c8];
  f16x8 pk1 = *(const f16x8*)&Kb[(size_t)r_1 * HD + c8];
  f16x8 pv0 = *(const f16x8*)&Vb[(size_t)r_0 * SL + c8];
  f16x8 pv1 = *(const f16x8*)&Vb[(size_t)r_1 * SL + c8];

  for (int e = t; e < 576; e += 256) {
    int p = e >> 6, c = e & 63;
    lev[p][c] = isbf ? ldbf(embv, (size_t)h * 576 + e) : ldf(embv, (size_t)h * 576 + e);
  }
  for (int e = t; e < 768; e += 256) ((float*)lsb)[e] = -1e30f;
  __syncthreads();                      // P1: lq/lev/lsb visible

  const f16x8 qf0 = *(const f16x8*)&lq[16 * wid + lid][quad * 8];
  const f16x8 qf1 = *(const f16x8*)&lq[16 * wid + lid][32 + quad * 8];

  // band bias via MFMA: A = emb_rel_k rows (m = p), B = qf (wave-local rows)
  // qf carries QSCALE = scale*log2e, so lbias lands in the same exp2 domain.
  {
    int row = h * 9 + (lid < 9 ? lid : 0);
    f16x8 ekf0, ekf1;
    if (!isbf) {
      const float* ek = (const float*)embk;
#pragma unroll
      for (int e = 0; e < 8; ++e) {
        ekf0[e] = (f16)ek[(size_t)row * HD + quad * 8 + e];
        ekf1[e] = (f16)ek[(size_t)row * HD + 32 + quad * 8 + e];
      }
    } else {
      const unsigned short* ek = (const unsigned short*)embk;
      u16x8 v0 = *(const u16x8*)&ek[(size_t)row * HD + quad * 8];
      u16x8 v1 = *(const u16x8*)&ek[(size_t)row * HD + 32 + quad * 8];
#pragma unroll
      for (int e = 0; e < 8; ++e) { ekf0[e] = (f16)bfb(v0[e]); ekf1[e] = (f16)bfb(v1[e]); }
    }
    f32x4 bd = (f32x4){0.f, 0.f, 0.f, 0.f};
    bd = __builtin_amdgcn_mfma_f32_16x16x32_f16(ekf0, qf0, bd, 0, 0, 0);
    bd = __builtin_amdgcn_mfma_f32_16x16x32_f16(ekf1, qf1, bd, 0, 0, 0);
#pragma unroll
    for (int r = 0; r < 4; ++r) {
      int p = quad * 4 + r;
      if (p < 9) lbias[16 * wid + lid][p] = bd[r];
    }
  }
  __syncthreads();                      // P2: all waves have their Q frags; bufk[0] now reusable

  const f16x4 ones4 = {(f16)1.f, (f16)1.f, (f16)1.f, (f16)1.f};

  f32x4 O[4];
  f32x4 Os = (f32x4){0.f, 0.f, 0.f, 0.f};
#pragma unroll
  for (int dt = 0; dt < 4; ++dt) O[dt] = (f32x4){0.f, 0.f, 0.f, 0.f};

  const int irow = 16 * wid + lid;

  int ib = 0;
  for (int j0 = 0; j0 < SL; j0 += 64, ib ^= 1) {
    // drain prefetch regs into LDS buf[ib] (write BEFORE barrier)
    *(f16x8*)&bufk[ib][r_0][c8] = pk0;
    *(f16x8*)&bufk[ib][r_1][c8] = pk1;
    *(f16x4*)&bufv[ib][r_0][colA] = __builtin_shufflevector(pv0, pv0, 0, 1, 2, 3);
    *(f16x4*)&bufv[ib][r_0][colB] = __builtin_shufflevector(pv0, pv0, 4, 5, 6, 7);
    *(f16x4*)&bufv[ib][r_1][colA] = __builtin_shufflevector(pv1, pv1, 0, 1, 2, 3);
    *(f16x4*)&bufv[ib][r_1][colB] = __builtin_shufflevector(pv1, pv1, 4, 5, 6, 7);
    __syncthreads();                    // the ONLY barrier in the loop

    // prefetch next tile (issued post-barrier; consumed next iter's write)
    if (j0 + 64 < SL) {
      pk0 = *(const f16x8*)&Kb[(size_t)(j0 + 64 + r_0) * HD + c8];
      pk1 = *(const f16x8*)&Kb[(size_t)(j0 + 64 + r_1) * HD + c8];
      pv0 = *(const f16x8*)&Vb[(size_t)r_0 * SL + j0 + 64 + c8];
      pv1 = *(const f16x8*)&Vb[(size_t)r_1 * SL + j0 + 64 + c8];
    }

    // S^T (scores in log2 domain)
    f32x4 sc[4];
#pragma unroll
    for (int jt = 0; jt < 4; ++jt) {
      f16x8 a0 = *(const f16x8*)&bufk[ib][jt * 16 + lid][quad * 8];
      f16x8 a1 = *(const f16x8*)&bufk[ib][jt * 16 + lid][32 + quad * 8];
      f32x4 z = (f32x4){0.f, 0.f, 0.f, 0.f};
      sc[jt] = __builtin_amdgcn_mfma_f32_16x16x32_f16(a0, qf0, z, 0, 0, 0);
      sc[jt] = __builtin_amdgcn_mfma_f32_16x16x32_f16(a1, qf1, sc[jt], 0, 0, 0);
    }

    if (j0 - i0 <= 64 && i0 - j0 <= 64) {
#pragma unroll
      for (int jt = 0; jt < 4; ++jt)
#pragma unroll
        for (int r = 0; r < 4; ++r) {
          int d = (j0 + jt * 16 + quad * 4 + r) - (i0 + irow) + WIN;
          if (d >= 0 && d <= 2 * WIN) {
            float s = sc[jt][r] + lbias[irow][d];
            sc[jt][r] = s;
            lsb[irow][d] = s;
          }
        }
    }

    f16x4 pb[4];
#pragma unroll
    for (int jt = 0; jt < 4; ++jt)
#pragma unroll
      for (int r = 0; r < 4; ++r)
        pb[jt][r] = (f16)fexp2(fminf(sc[jt][r], SCLAMP2));

#pragma unroll
    for (int jt = 0; jt < 4; ++jt)
      Os = __builtin_amdgcn_mfma_f32_16x16x16f16(ones4, pb[jt], Os, 0, 0, 0);

#pragma unroll
    for (int dt = 0; dt < 4; ++dt) {
      f16x8 va01 = *(const f16x8*)&bufv[ib][dt * 16 + lid][quad * 16];
      f16x8 va23 = *(const f16x8*)&bufv[ib][dt * 16 + lid][quad * 16 + 8];
      O[dt] = __builtin_amdgcn_mfma_f32_16x16x16f16(
                __builtin_shufflevector(va01, va01, 0, 1, 2, 3), pb[0], O[dt], 0, 0, 0);
      O[dt] = __builtin_amdgcn_mfma_f32_16x16x16f16(
                __builtin_shufflevector(va01, va01, 4, 5, 6, 7), pb[1], O[dt], 0, 0, 0);
      O[dt] = __builtin_amdgcn_mfma_f32_16x16x16f16(
                __builtin_shufflevector(va23, va23, 0, 1, 2, 3), pb[2], O[dt], 0, 0, 0);
      O[dt] = __builtin_amdgcn_mfma_f32_16x16x16f16(
                __builtin_shufflevector(va23, va23, 4, 5, 6, 7), pb[3], O[dt], 0, 0, 0);
    }
  }

  if (quad == 0) ll64[irow] = Os[0];
  __syncthreads();

  for (int e = t; e < 576; e += 256) {
    int r = e / 9, p = e - r * 9;
    lsb[r][p] = fexp2(fminf(lsb[r][p], SCLAMP2)) * __builtin_amdgcn_rcpf(ll64[r]);
  }
  __syncthreads();

  {
    const float rl = __builtin_amdgcn_rcpf(Os[0]);
    float lp[9];
#pragma unroll
    for (int p = 0; p < 9; ++p) lp[p] = lsb[irow][p];
    float val[4][4];
#pragma unroll
    for (int dt = 0; dt < 4; ++dt)
#pragma unroll
      for (int r = 0; r < 4; ++r) val[dt][r] = O[dt][r] * rl;
#pragma unroll
    for (int p = 0; p < 9; ++p)
#pragma unroll
      for (int dt = 0; dt < 4; ++dt)
#pragma unroll
        for (int r = 0; r < 4; ++r)
          val[dt][r] += lp[p] * lev[p][dt * 16 + quad * 4 + r];
#pragma unroll
    for (int dt = 0; dt < 4; ++dt) {
      f16x4 vv;
#pragma unroll
      for (int r = 0; r < 4; ++r) vv[r] = (f16)val[dt][r];
      *(f16x4*)&lo[irow][dt * 16 + quad * 4] = vv;
    }
  }
  __syncthreads();

  {
    const int l = t >> 2, seg = t & 3;
    f16* dst = &R2t[((size_t)b * SL + i0 + l) * CH + h * 64 + seg * 16];
    *(f16x8*)dst       = *(const f16x8*)&lo[l][seg * 16];
    *(f16x8*)(dst + 8) = *(const f16x8*)&lo[l][seg * 16 + 8];
  }
}

// ---------------------------------------------------------------------------
// K3: output projection, 128x128-tile fp16 MFMA GEMM.
// round-14: LDS pad 72 -> 76 (bank-conflict fix).
// ---------------------------------------------------------------------------
__global__ __launch_bounds__(256) void out_k(
    const f16* __restrict__ wh, const float* __restrict__ bh, const f16* __restrict__ R2t,
    void* __restrict__ out, const int* __restrict__ flag)
{
  __shared__ f16 sm[2][128][PAD];

  const int isbf = *flag;
  const int t   = threadIdx.x;
  const int l0  = blockIdx.x * 128;
  const int m0  = blockIdx.y * 128;
  const int b   = blockIdx.z;
  const int wid = t >> 6, lane = t & 63;
  const int quad = lane >> 4, lid = lane & 15;
  const int rw = wid >> 1, cw = wid & 1;

  const f16* wg = wh + (size_t)3 * CH * CH;

  f32x4 acc[4][4];
#pragma unroll
  for (int mt = 0; mt < 4; ++mt)
#pragma unroll
    for (int nt = 0; nt < 4; ++nt) acc[mt][nt] = (f32x4){0.f, 0.f, 0.f, 0.f};

  for (int c0 = 0; c0 < CH; c0 += 64) {
    __syncthreads();
#pragma unroll
    for (int k = 0; k < 4; ++k) {
      int cidx = t + k * 256;
      int r = cidx >> 3, c8 = (cidx & 7) * 8;
      *(f16x8*)&sm[0][r][c8] = *(const f16x8*)&wg[(size_t)(m0 + r) * CH + c0 + c8];
      *(f16x8*)&sm[1][r][c8] = *(const f16x8*)&R2t[((size_t)b * SL + l0 + r) * CH + c0 + c8];
    }
    __syncthreads();
#pragma unroll
    for (int kk = 0; kk < 2; ++kk) {
      f16x8 bf[4];
#pragma unroll
      for (int nt = 0; nt < 4; ++nt)
        bf[nt] = *(const f16x8*)&sm[1][cw * 64 + nt * 16 + lid][kk * 32 + quad * 8];
#pragma unroll
      for (int mt = 0; mt < 4; ++mt) {
        f16x8 af = *(const f16x8*)&sm[0][rw * 64 + mt * 16 + lid][kk * 32 + quad * 8];
#pragma unroll
        for (int nt = 0; nt < 4; ++nt)
          acc[mt][nt] = __builtin_amdgcn_mfma_f32_16x16x32_f16(af, bf[nt], acc[mt][nt], 0, 0, 0);
      }
    }
  }

  float bias[4][4];
#pragma unroll
  for (int mt = 0; mt < 4; ++mt)
#pragma unroll
    for (int r = 0; r < 4; ++r)
      bias[mt][r] = bh[3 * CH + m0 + rw * 64 + mt * 16 + quad * 4 + r];

  if (isbf) {
    __syncthreads();                    // protect LDS overlay
    unsigned short (*lo4)[64][PAD] = (unsigned short(*)[64][PAD])sm;  // wave-private
#pragma unroll
    for (int mt = 0; mt < 4; ++mt)
#pragma unroll
      for (int nt = 0; nt < 4; ++nt)
#pragma unroll
        for (int r = 0; r < 4; ++r)
          lo4[wid][mt * 16 + quad * 4 + r][nt * 16 + lid] =
            f2bf_rne(acc[mt][nt][r] + bias[mt][r]);
    __builtin_amdgcn_s_waitcnt(0);      // wave-local LDS drain
    unsigned short* base = (unsigned short*)out
      + ((size_t)b * CH + m0 + rw * 64) * SL + l0 + cw * 64;
#pragma unroll
    for (int p = 0; p < 8; ++p) {
      int mr = p * 8 + (lane >> 3), seg = lane & 7;
      *(u16x8*)&base[(size_t)mr * SL + seg * 8] = *(const u16x8*)&lo4[wid][mr][seg * 8];
    }
  } else {
#pragma unroll
    for (int mt = 0; mt < 4; ++mt)
#pragma unroll
      for (int nt = 0; nt < 4; ++nt)
#pragma unroll
        for (int r = 0; r < 4; ++r) {
          int m = m0 + rw * 64 + mt * 16 + quad * 4 + r;
          int l = l0 + cw * 64 + nt * 16 + lid;
          ((float*)out)[((size_t)b * CH + m) * SL + l] = acc[mt][nt][r] + bias[mt][r];
        }
  }
}

extern "C" void kernel_launch(void* const* d_in, const int* in_sizes, int n_in,
                              void* d_out, int out_size, void* d_ws, size_t ws_size,
                              hipStream_t stream) {
  (void)in_sizes; (void)n_in; (void)out_size; (void)ws_size;
  const void* x  = d_in[0];
  const void* wq = d_in[1]; const void* bq = d_in[2];
  const void* wk = d_in[3]; const void* bk = d_in[4];
  const void* wv = d_in[5]; const void* bv = d_in[6];
  const void* wo = d_in[7]; const void* bo = d_in[8];
  const void* ek = d_in[9]; const void* ev = d_in[10];

  const size_t NQ = (size_t)NB * NH * SL * HD;     // 3,145,728 per tensor
  const size_t NX = (size_t)NB * SL * CH;          // 3,145,728
  char* w = (char*)d_ws;
  int*   flag = (int*)w;                 w += 256;
  f16*   wh   = (f16*)w;                 w += 4 * CH * CH * sizeof(f16);   // 1.18 MB
  float* bh   = (float*)w;               w += 4 * CH * sizeof(float);
  f16*   xt   = (f16*)w;                 w += NX * sizeof(f16);
  f16*   Q    = (f16*)w;                 w += NQ * sizeof(f16);
  f16*   K    = (f16*)w;                 w += NQ * sizeof(f16);
  f16*   Vt   = (f16*)w;                 w += NQ * sizeof(f16);
  f16*   R2t  = (f16*)w;                 w += NX * sizeof(f16);

  cvt_k   <<<1345, 256, 0, stream>>>(wq, wk, wv, wo, bq, bk, bv, bo, x, wh, bh, xt, flag);
  qkv_k   <<<dim3(8, 9, NB), 256, 0, stream>>>(wh, bh, xt, Q, K, Vt);
  attn_k  <<<768, 256, 0, stream>>>(Q, K, Vt, ek, ev, R2t, flag);
  out_k   <<<dim3(8, 3, NB), 256, 0, stream>>>(wh, bh, R2t, d_out, flag);
}

// Round 4
// 147.261 us; speedup vs baseline: 1.0016x; 1.0016x over previous
//
#include <hip/hip_runtime.h>
#include <hip/hip_bf16.h>

#define NB 8
#define CH 384
#define SL 1024
#define NH 6
#define HD 64
#define WIN 4
#define LOG2E 1.44269504088896340736f
#define SCALE 0.125f            // 1/sqrt(64)
#define QSCALE (SCALE * LOG2E)  // fold log2(e): attention runs in exp2 domain
#define SCLAMP2 14.4269504f     // 10*log2e; exp2(14.43)=e^10=22026 < fp16 max
#define PAD 72                  // r2 measured-best; 76 was neutral (r3)

typedef _Float16 f16;
typedef f16   f16x8 __attribute__((ext_vector_type(8)));
typedef f16   f16x4 __attribute__((ext_vector_type(4)));
typedef float f32x4 __attribute__((ext_vector_type(4)));
typedef unsigned short u16x8 __attribute__((ext_vector_type(8)));
typedef unsigned short u16x4 __attribute__((ext_vector_type(4)));

static __device__ __forceinline__ unsigned short f2bf_rne(float f) {
  unsigned int u = __float_as_uint(f);
  unsigned int r = (u + 0x7fffu + ((u >> 16) & 1u)) >> 16;
  return (unsigned short)r;
}
static __device__ __forceinline__ float bfb(unsigned short u) {   // bf16 bits -> f32
  return __uint_as_float((unsigned int)u << 16);
}
static __device__ __forceinline__ float ldbf(const void* p, size_t i) {
  return bfb(((const unsigned short*)p)[i]);
}
static __device__ __forceinline__ float ldf(const void* p, size_t i) {
  return ((const float*)p)[i];
}
// raw v_exp_f32 (2^x); safe: upstream clamps the high side, low side flushes to 0
static __device__ __forceinline__ float fexp2(float x) {
  return __builtin_amdgcn_exp2f(x);
}

// raw barrier: LDS-visibility only, NO vmcnt drain (loop has no global stores;
// prefetch loads must survive across the barrier — HK T3/T4 pattern).
#define BAR() do {                                            \
    asm volatile("s_waitcnt lgkmcnt(0)" ::: "memory");        \
    __builtin_amdgcn_s_barrier();                             \
    asm volatile("" ::: "memory");                            \
  } while (0)

// ---------------------------------------------------------------------------
// Kc: merged conversions + inline dtype probe (unchanged).
// ---------------------------------------------------------------------------
__global__ __launch_bounds__(256) void cvt_k(
    const void* __restrict__ w0, const void* __restrict__ w1,
    const void* __restrict__ w2, const void* __restrict__ w3,
    const void* __restrict__ b0, const void* __restrict__ b1,
    const void* __restrict__ b2, const void* __restrict__ b3,
    const void* __restrict__ x,
    f16* __restrict__ wh, float* __restrict__ bh, f16* __restrict__ xt,
    int* __restrict__ flag)
{
  __shared__ f16 lt_[64][72];
  __shared__ int sflag;
  const int bx = blockIdx.x, t = threadIdx.x;

  {
    int cnt = 0;
    if (t < 64) {
      const unsigned int* xu = (const unsigned int*)x;
#pragma unroll
      for (int i = 0; i < 4; ++i) {
        unsigned int e = (xu[t * 4 + i] >> 7) & 0xFF;
        if (e >= 110 && e <= 140) ++cnt;
      }
#pragma unroll
      for (int s = 1; s < 64; s <<= 1) cnt += __shfl_xor(cnt, s);
      if (t == 0) sflag = (cnt >= 128) ? 1 : 0;
    }
    __syncthreads();
  }
  const int isbf = sflag;

  if (bx < 576) {                       // 144 blocks per matrix
    int g = bx / 144;
    const void* src = (g == 0) ? w0 : (g == 1) ? w1 : (g == 2) ? w2 : w3;
    size_t idx = (size_t)(bx % 144) * 1024 + t * 4;
    f16* dst = wh + (size_t)g * CH * CH + idx;
    f16x4 o;
    if (!isbf) {
      float4 v = *(const float4*)((const float*)src + idx);
      o[0] = (f16)v.x; o[1] = (f16)v.y; o[2] = (f16)v.z; o[3] = (f16)v.w;
    } else {
      u16x4 v = *(const u16x4*)((const unsigned short*)src + idx);
#pragma unroll
      for (int j = 0; j < 4; ++j) o[j] = (f16)bfb(v[j]);
    }
    *(f16x4*)dst = o;
    return;
  }
  if (bx == 576) {                      // biases + publish flag
    if (t == 0) *flag = isbf;
    for (int e = t; e < 4 * CH; e += 256) {
      int g = e / CH, i = e - g * CH;
      const void* src = (g == 0) ? b0 : (g == 1) ? b1 : (g == 2) ? b2 : b3;
      bh[e] = isbf ? ldbf(src, i) : ldf(src, i);
    }
    return;
  }
  // x transpose: e in 0..767
  const int e  = bx - 577;
  const int l0 = (e & 15) * 64;
  const int c0 = ((e >> 4) % 6) * 64;
  const int b  = e / 96;
  const int row = t >> 4, lseg = t & 15;

  if (!isbf) {
    const float* xf = (const float*)x;
#pragma unroll
    for (int k = 0; k < 4; ++k) {
      int c = c0 + row + 16 * k;
      float4 v = *(const float4*)&xf[((size_t)b * CH + c) * SL + l0 + lseg * 4];
      lt_[lseg * 4 + 0][row + 16 * k] = (f16)v.x;
      lt_[lseg * 4 + 1][row + 16 * k] = (f16)v.y;
      lt_[lseg * 4 + 2][row + 16 * k] = (f16)v.z;
      lt_[lseg * 4 + 3][row + 16 * k] = (f16)v.w;
    }
  } else {
    const unsigned short* xu = (const unsigned short*)x;
#pragma unroll
    for (int k = 0; k < 4; ++k) {
      int c = c0 + row + 16 * k;
      u16x4 v = *(const u16x4*)&xu[((size_t)b * CH + c) * SL + l0 + lseg * 4];
#pragma unroll
      for (int j = 0; j < 4; ++j)
        lt_[lseg * 4 + j][row + 16 * k] = (f16)bfb(v[j]);
    }
  }
  __syncthreads();
  const int l = t >> 2, seg = t & 3;
  f16* dst = &xt[((size_t)b * SL + l0 + l) * CH + c0 + seg * 16];
  *(f16x8*)dst       = *(const f16x8*)&lt_[l][seg * 16];
  *(f16x8*)(dst + 8) = *(const f16x8*)&lt_[l][seg * 16 + 8];
}

// ---------------------------------------------------------------------------
// K1: QKV projection, 128x128-tile fp16 MFMA GEMM (r2 version, pad 72).
// ---------------------------------------------------------------------------
__global__ __launch_bounds__(256) void qkv_k(
    const f16* __restrict__ wh, const float* __restrict__ bh, const f16* __restrict__ xt,
    f16* __restrict__ Q, f16* __restrict__ K, f16* __restrict__ Vt)
{
  __shared__ f16 sm[2][128][PAD];

  const int t   = threadIdx.x;
  const int l0  = blockIdx.x * 128;
  const int mty = blockIdx.y;           // 0..8
  const int b   = blockIdx.z;
  const int wid = t >> 6, lane = t & 63;
  const int quad = lane >> 4, lid = lane & 15;
  const int rw = wid >> 1, cw = wid & 1;

  const int g0   = mty / 3;             // 0=Q, 1=K, 2=V
  const int m128 = (mty % 3) * 128;
  const f16* wg  = wh + (size_t)g0 * CH * CH;

  f32x4 acc[4][4];
#pragma unroll
  for (int mt = 0; mt < 4; ++mt)
#pragma unroll
    for (int nt = 0; nt < 4; ++nt) acc[mt][nt] = (f32x4){0.f, 0.f, 0.f, 0.f};

  for (int c0 = 0; c0 < CH; c0 += 64) {
    __syncthreads();
#pragma unroll
    for (int k = 0; k < 4; ++k) {
      int cidx = t + k * 256;
      int r = cidx >> 3, c8 = (cidx & 7) * 8;
      *(f16x8*)&sm[0][r][c8] = *(const f16x8*)&wg[(size_t)(m128 + r) * CH + c0 + c8];
      *(f16x8*)&sm[1][r][c8] = *(const f16x8*)&xt[((size_t)b * SL + l0 + r) * CH + c0 + c8];
    }
    __syncthreads();
#pragma unroll
    for (int kk = 0; kk < 2; ++kk) {
      f16x8 bf[4];
#pragma unroll
      for (int nt = 0; nt < 4; ++nt)
        bf[nt] = *(const f16x8*)&sm[1][cw * 64 + nt * 16 + lid][kk * 32 + quad * 8];
#pragma unroll
      for (int mt = 0; mt < 4; ++mt) {
        f16x8 af = *(const f16x8*)&sm[0][rw * 64 + mt * 16 + lid][kk * 32 + quad * 8];
#pragma unroll
        for (int nt = 0; nt < 4; ++nt)
          acc[mt][nt] = __builtin_amdgcn_mfma_f32_16x16x32_f16(af, bf[nt], acc[mt][nt], 0, 0, 0);
      }
    }
  }
  __syncthreads();                      // protect LDS overlay

  const int h = (mty % 3) * 2 + rw;
  float bias[4][4];
#pragma unroll
  for (int mt = 0; mt < 4; ++mt)
#pragma unroll
    for (int r = 0; r < 4; ++r)
      bias[mt][r] = bh[g0 * CH + m128 + rw * 64 + mt * 16 + quad * 4 + r];
  const float osc = (g0 == 0) ? QSCALE : 1.0f;

  f16 (*lo4)[64][PAD] = (f16(*)[64][PAD])sm;   // wave-private overlay

  if (g0 < 2) {                         // Q or K: lo[l][d], store (B,H,L,64)
#pragma unroll
    for (int mt = 0; mt < 4; ++mt)
#pragma unroll
      for (int nt = 0; nt < 4; ++nt) {
        f16x4 vv;
#pragma unroll
        for (int r = 0; r < 4; ++r)
          vv[r] = (f16)((acc[mt][nt][r] + bias[mt][r]) * osc);
        *(f16x4*)&lo4[wid][nt * 16 + lid][mt * 16 + quad * 4] = vv;
      }
    __builtin_amdgcn_s_waitcnt(0);
    f16* base = ((g0 == 0) ? Q : K) + ((size_t)(b * NH + h) * SL + l0 + cw * 64) * HD;
#pragma unroll
    for (int p = 0; p < 8; ++p) {
      int lr = p * 8 + (lane >> 3), seg = lane & 7;
      *(f16x8*)&base[(size_t)lr * HD + seg * 8] = *(const f16x8*)&lo4[wid][lr][seg * 8];
    }
  } else {                              // V: lo[d][l], store (B,H,64,L)
#pragma unroll
    for (int mt = 0; mt < 4; ++mt)
#pragma unroll
      for (int nt = 0; nt < 4; ++nt)
#pragma unroll
        for (int r = 0; r < 4; ++r)
          lo4[wid][mt * 16 + quad * 4 + r][nt * 16 + lid] =
            (f16)(acc[mt][nt][r] + bias[mt][r]);
    __builtin_amdgcn_s_waitcnt(0);
    f16* base = Vt + ((size_t)(b * NH + h) * HD) * SL + l0 + cw * 64;
#pragma unroll
    for (int p = 0; p < 8; ++p) {
      int dr = p * 8 + (lane >> 3), seg = lane & 7;
      *(f16x8*)&base[(size_t)dr * SL + seg * 8] = *(const f16x8*)&lo4[wid][dr][seg * 8];
    }
  }
}

// ---------------------------------------------------------------------------
// K2: MFMA flash attention — round-15 quadrant re-ownership.
// Wave w=(ih=w>>1, jh=w&1) owns the 32j x 32i quadrant of S^T: reads only its
// K half-strip (4xb128) + V k-slices (8xb64) per iter (~2.5x less LDS read
// traffic than the old all-waves-read-everything scheme; the K/V fragment
// reads were 4x redundant across waves). P stays wave-local (j = PV's k-dim).
// Cost: 2x accumulators + one-time 32KB cross-wave O reduction, after which
// wave w owns i-strip w and the original epilogue runs verbatim.
// Barriers in the loop are raw lgkmcnt(0)+s_barrier (no vmcnt drain): loop
// has no global stores, so prefetch loads ride across barriers and are only
// waited via their data-dependent vmcnt at the next ds_write.
// ---------------------------------------------------------------------------
__global__ __launch_bounds__(256, 3) void attn_k(
    const f16* __restrict__ Qs, const f16* __restrict__ Kg, const f16* __restrict__ Vtg,
    const void* __restrict__ embk, const void* __restrict__ embv,
    f16* __restrict__ R2t, const int* __restrict__ flag)
{
  __shared__ f16 bufall[4][64][PAD];    // [0..1] = K dbuf, [2..3] = V dbuf
  __shared__ float lbias[64][12];
  __shared__ float lsb[64][12];
  __shared__ float lev[9][64];
  __shared__ float ll64[64];
  __shared__ float lred[4][2][16];

  const int isbf = *flag;
  const int t    = threadIdx.x;

  const int id   = blockIdx.x;
  const int xcd  = id & 7;
  const int kk   = id >> 3;
  const int pair = (kk % 6) * 8 + xcd;
  const int i0   = (kk / 6) * 64;
  const int b    = pair / NH;
  const int h    = pair % NH;

  const int wid  = t >> 6;
  const int lane = t & 63;
  const int quad = lane >> 4;
  const int lid  = lane & 15;
  const int ih   = wid >> 1;            // i-half owned
  const int jh   = wid & 1;             // j-half owned
  const int irow = 16 * wid + lid;      // epilogue i-row (post-reduction)

  const f16* Qb = Qs  + ((size_t)(b * NH + h) * SL) * HD;
  const f16* Kb = Kg  + ((size_t)(b * NH + h) * SL) * HD;
  const f16* Vb = Vtg + ((size_t)(b * NH + h) * HD) * SL;

  f16 (*bufk)[64][PAD] = &bufall[0];
  f16 (*bufv)[64][PAD] = &bufall[2];
  f16 (* const lq)[PAD] = bufall[0];    // prologue overlay
  f16 (* const lo)[PAD] = bufall[0];    // epilogue overlay

  const int r_0 = t >> 3, c8 = (t & 7) * 8;
  const int r_1 = (t + 256) >> 3;

  // stage Q tile into bufall[0]
#pragma unroll
  for (int k = 0; k < 2; ++k) {
    int c = t + k * 256, r = c >> 3, cc8 = (c & 7) * 8;
    *(f16x8*)&lq[r][cc8] = *(const f16x8*)&Qb[(size_t)(i0 + r) * HD + cc8];
  }
  // prefetch tile 0 into registers (V staged straight, no permute)
  f16x8 pk0 = *(const f16x8*)&Kb[(size_t)r_0 * HD + c8];
  f16x8 pk1 = *(const f16x8*)&Kb[(size_t)r_1 * HD + c8];
  f16x8 pv0 = *(const f16x8*)&Vb[(size_t)r_0 * SL + c8];
  f16x8 pv1 = *(const f16x8*)&Vb[(size_t)r_1 * SL + c8];

  for (int e = t; e < 576; e += 256) {
    int p = e >> 6, c = e & 63;
    lev[p][c] = isbf ? ldbf(embv, (size_t)h * 576 + e) : ldf(embv, (size_t)h * 576 + e);
  }
  for (int e = t; e < 768; e += 256) ((float*)lsb)[e] = -1e30f;
  BAR();                                // P1: lq/lev/lsb visible (no vmem drain)

  // Q fragments for the wave's i-half: nt in {0,1} -> i-strip ih*32 + nt*16
  f16x8 qn0[2], qn1[2];
#pragma unroll
  for (int nt = 0; nt < 2; ++nt) {
    qn0[nt] = *(const f16x8*)&lq[ih * 32 + nt * 16 + lid][quad * 8];
    qn1[nt] = *(const f16x8*)&lq[ih * 32 + nt * 16 + lid][32 + quad * 8];
  }

  // band bias via MFMA (strip wid = (ih, nt=jh)): table lbias[i][d], i-indexed
  {
    int row = h * 9 + (lid < 9 ? lid : 0);
    f16x8 ekf0, ekf1;
    if (!isbf) {
      const float* ek = (const float*)embk;
#pragma unroll
      for (int e = 0; e < 8; ++e) {
        ekf0[e] = (f16)ek[(size_t)row * HD + quad * 8 + e];
        ekf1[e] = (f16)ek[(size_t)row * HD + 32 + quad * 8 + e];
      }
    } else {
      const unsigned short* ek = (const unsigned short*)embk;
      u16x8 v0 = *(const u16x8*)&ek[(size_t)row * HD + quad * 8];
      u16x8 v1 = *(const u16x8*)&ek[(size_t)row * HD + 32 + quad * 8];
#pragma unroll
      for (int e = 0; e < 8; ++e) { ekf0[e] = (f16)bfb(v0[e]); ekf1[e] = (f16)bfb(v1[e]); }
    }
    f32x4 bd = (f32x4){0.f, 0.f, 0.f, 0.f};
    bd = __builtin_amdgcn_mfma_f32_16x16x32_f16(ekf0, qn0[jh], bd, 0, 0, 0);
    bd = __builtin_amdgcn_mfma_f32_16x16x32_f16(ekf1, qn1[jh], bd, 0, 0, 0);
#pragma unroll
    for (int r = 0; r < 4; ++r) {
      int p = quad * 4 + r;
      if (p < 9) lbias[irow][p] = bd[r];
    }
  }
  BAR();                                // P2: Q frags read; bufall[0] reusable

  const f16x4 ones4 = {(f16)1.f, (f16)1.f, (f16)1.f, (f16)1.f};

  f32x4 Op[2][4];                       // [nt][dt] partial O (j in jh-half)
  f32x4 Os[2];                          // [nt] partial l
#pragma unroll
  for (int nt = 0; nt < 2; ++nt) {
    Os[nt] = (f32x4){0.f, 0.f, 0.f, 0.f};
#pragma unroll
    for (int dt = 0; dt < 4; ++dt) Op[nt][dt] = (f32x4){0.f, 0.f, 0.f, 0.f};
  }

  int ib = 0;
  for (int j0 = 0; j0 < SL; j0 += 64, ib ^= 1) {
    // drain prefetch regs into LDS buf[ib] (write BEFORE barrier)
    *(f16x8*)&bufk[ib][r_0][c8] = pk0;
    *(f16x8*)&bufk[ib][r_1][c8] = pk1;
    *(f16x8*)&bufv[ib][r_0][c8] = pv0;
    *(f16x8*)&bufv[ib][r_1][c8] = pv1;
    BAR();                              // LDS-visibility only; vmem stays in flight

    if (j0 + 64 < SL) {
      pk0 = *(const f16x8*)&Kb[(size_t)(j0 + 64 + r_0) * HD + c8];
      pk1 = *(const f16x8*)&Kb[(size_t)(j0 + 64 + r_1) * HD + c8];
      pv0 = *(const f16x8*)&Vb[(size_t)r_0 * SL + j0 + 64 + c8];
      pv1 = *(const f16x8*)&Vb[(size_t)r_1 * SL + j0 + 64 + c8];
    }

    // K fragments: only the wave's jh half-strip (jt in {0,1})
    f16x8 a00 = *(const f16x8*)&bufk[ib][jh * 32 + lid][quad * 8];
    f16x8 a10 = *(const f16x8*)&bufk[ib][jh * 32 + lid][32 + quad * 8];
    f16x8 a01 = *(const f16x8*)&bufk[ib][jh * 32 + 16 + lid][quad * 8];
    f16x8 a11 = *(const f16x8*)&bufk[ib][jh * 32 + 16 + lid][32 + quad * 8];

    // S^T quadrant (scores in log2 domain): sc[jt][nt]
    f32x4 sc[2][2];
#pragma unroll
    for (int nt = 0; nt < 2; ++nt) {
      f32x4 z = (f32x4){0.f, 0.f, 0.f, 0.f};
      sc[0][nt] = __builtin_amdgcn_mfma_f32_16x16x32_f16(a00, qn0[nt], z, 0, 0, 0);
      sc[0][nt] = __builtin_amdgcn_mfma_f32_16x16x32_f16(a10, qn1[nt], sc[0][nt], 0, 0, 0);
      sc[1][nt] = __builtin_amdgcn_mfma_f32_16x16x32_f16(a01, qn0[nt], z, 0, 0, 0);
      sc[1][nt] = __builtin_amdgcn_mfma_f32_16x16x32_f16(a11, qn1[nt], sc[1][nt], 0, 0, 0);
    }

    if (j0 - i0 <= 64 && i0 - j0 <= 64) {
#pragma unroll
      for (int jt = 0; jt < 2; ++jt)
#pragma unroll
        for (int nt = 0; nt < 2; ++nt)
#pragma unroll
          for (int r = 0; r < 4; ++r) {
            int jl = jh * 32 + jt * 16 + quad * 4 + r;
            int il = ih * 32 + nt * 16 + lid;
            int d = (j0 + jl) - (i0 + il) + WIN;
            if (d >= 0 && d <= 2 * WIN) {
              float s = sc[jt][nt][r] + lbias[il][d];
              sc[jt][nt][r] = s;
              lsb[il][d] = s;
            }
          }
    }

    f16x4 pb[2][2];
#pragma unroll
    for (int jt = 0; jt < 2; ++jt)
#pragma unroll
      for (int nt = 0; nt < 2; ++nt)
#pragma unroll
        for (int r = 0; r < 4; ++r)
          pb[jt][nt][r] = (f16)fexp2(fminf(sc[jt][nt][r], SCLAMP2));

#pragma unroll
    for (int nt = 0; nt < 2; ++nt) {
      Os[nt] = __builtin_amdgcn_mfma_f32_16x16x16f16(ones4, pb[0][nt], Os[nt], 0, 0, 0);
      Os[nt] = __builtin_amdgcn_mfma_f32_16x16x16f16(ones4, pb[1][nt], Os[nt], 0, 0, 0);
    }

    // PV: V k-slices for the jh half only (b64 reads, straight layout)
#pragma unroll
    for (int dt = 0; dt < 4; ++dt) {
      f16x4 vf0 = *(const f16x4*)&bufv[ib][dt * 16 + lid][jh * 32 + quad * 4];
      f16x4 vf1 = *(const f16x4*)&bufv[ib][dt * 16 + lid][jh * 32 + 16 + quad * 4];
#pragma unroll
      for (int nt = 0; nt < 2; ++nt) {
        Op[nt][dt] = __builtin_amdgcn_mfma_f32_16x16x16f16(vf0, pb[0][nt], Op[nt][dt], 0, 0, 0);
        Op[nt][dt] = __builtin_amdgcn_mfma_f32_16x16x16f16(vf1, pb[1][nt], Op[nt][dt], 0, 0, 0);
      }
    }
  }

  // ---- cross-wave reduction: strip s gets contribs from waves (s>>1)*2(+1) ----
  __syncthreads();                      // all bufall reads done
  float* red = (float*)bufall;          // 32 slots x 1KB = 32KB (fits 36.8KB)
#pragma unroll
  for (int nt = 0; nt < 2; ++nt)
#pragma unroll
    for (int dt = 0; dt < 4; ++dt)
      *(f32x4*)&red[(((wid * 2 + nt) * 4 + dt) * 64 + lane) * 4] = Op[nt][dt];
  if (quad == 0) {
    lred[wid][0][lid] = Os[0][0];       // l rows are identical across m: take r=0
    lred[wid][1][lid] = Os[1][0];
  }
  __syncthreads();

  const int u0w = (wid >> 1) * 2, u1w = u0w + 1, ntw = wid & 1;
  f32x4 O[4];
#pragma unroll
  for (int dt = 0; dt < 4; ++dt) {
    f32x4 xA = *(const f32x4*)&red[(((u0w * 2 + ntw) * 4 + dt) * 64 + lane) * 4];
    f32x4 xB = *(const f32x4*)&red[(((u1w * 2 + ntw) * 4 + dt) * 64 + lane) * 4];
    O[dt] = xA + xB;
  }
  const float lsum = lred[u0w][ntw][lid] + lred[u1w][ntw][lid];
  if (quad == 0) ll64[irow] = lsum;
  __syncthreads();                      // red reads done; ll64 visible

  for (int e = t; e < 576; e += 256) {
    int r = e / 9, p = e - r * 9;
    lsb[r][p] = fexp2(fminf(lsb[r][p], SCLAMP2)) * __builtin_amdgcn_rcpf(ll64[r]);
  }
  __syncthreads();

  {
    const float rl = __builtin_amdgcn_rcpf(lsum);
    float lp[9];
#pragma unroll
    for (int p = 0; p < 9; ++p) lp[p] = lsb[irow][p];
    float val[4][4];
#pragma unroll
    for (int dt = 0; dt < 4; ++dt)
#pragma unroll
      for (int r = 0; r < 4; ++r) val[dt][r] = O[dt][r] * rl;
#pragma unroll
    for (int p = 0; p < 9; ++p)
#pragma unroll
      for (int dt = 0; dt < 4; ++dt)
#pragma unroll
        for (int r = 0; r < 4; ++r)
          val[dt][r] += lp[p] * lev[p][dt * 16 + quad * 4 + r];
#pragma unroll
    for (int dt = 0; dt < 4; ++dt) {
      f16x4 vv;
#pragma unroll
      for (int r = 0; r < 4; ++r) vv[r] = (f16)val[dt][r];
      *(f16x4*)&lo[irow][dt * 16 + quad * 4] = vv;
    }
  }
  __syncthreads();

  {
    const int l = t >> 2, seg = t & 3;
    f16* dst = &R2t[((size_t)b * SL + i0 + l) * CH + h * 64 + seg * 16];
    *(f16x8*)dst       = *(const f16x8*)&lo[l][seg * 16];
    *(f16x8*)(dst + 8) = *(const f16x8*)&lo[l][seg * 16 + 8];
  }
}

// ---------------------------------------------------------------------------
// K3: output projection, 128x128-tile fp16 MFMA GEMM (r2 version, pad 72).
// ---------------------------------------------------------------------------
__global__ __launch_bounds__(256) void out_k(
    const f16* __restrict__ wh, const float* __restrict__ bh, const f16* __restrict__ R2t,
    void* __restrict__ out, const int* __restrict__ flag)
{
  __shared__ f16 sm[2][128][PAD];

  const int isbf = *flag;
  const int t   = threadIdx.x;
  const int l0  = blockIdx.x * 128;
  const int m0  = blockIdx.y * 128;
  const int b   = blockIdx.z;
  const int wid = t >> 6, lane = t & 63;
  const int quad = lane >> 4, lid = lane & 15;
  const int rw = wid >> 1, cw = wid & 1;

  const f16* wg = wh + (size_t)3 * CH * CH;

  f32x4 acc[4][4];
#pragma unroll
  for (int mt = 0; mt < 4; ++mt)
#pragma unroll
    for (int nt = 0; nt < 4; ++nt) acc[mt][nt] = (f32x4){0.f, 0.f, 0.f, 0.f};

  for (int c0 = 0; c0 < CH; c0 += 64) {
    __syncthreads();
#pragma unroll
    for (int k = 0; k < 4; ++k) {
      int cidx = t + k * 256;
      int r = cidx >> 3, c8 = (cidx & 7) * 8;
      *(f16x8*)&sm[0][r][c8] = *(const f16x8*)&wg[(size_t)(m0 + r) * CH + c0 + c8];
      *(f16x8*)&sm[1][r][c8] = *(const f16x8*)&R2t[((size_t)b * SL + l0 + r) * CH + c0 + c8];
    }
    __syncthreads();
#pragma unroll
    for (int kk = 0; kk < 2; ++kk) {
      f16x8 bf[4];
#pragma unroll
      for (int nt = 0; nt < 4; ++nt)
        bf[nt] = *(const f16x8*)&sm[1][cw * 64 + nt * 16 + lid][kk * 32 + quad * 8];
#pragma unroll
      for (int mt = 0; mt < 4; ++mt) {
        f16x8 af = *(const f16x8*)&sm[0][rw * 64 + mt * 16 + lid][kk * 32 + quad * 8];
#pragma unroll
        for (int nt = 0; nt < 4; ++nt)
          acc[mt][nt] = __builtin_amdgcn_mfma_f32_16x16x32_f16(af, bf[nt], acc[mt][nt], 0, 0, 0);
      }
    }
  }

  float bias[4][4];
#pragma unroll
  for (int mt = 0; mt < 4; ++mt)
#pragma unroll
    for (int r = 0; r < 4; ++r)
      bias[mt][r] = bh[3 * CH + m0 + rw * 64 + mt * 16 + quad * 4 + r];

  if (isbf) {
    __syncthreads();                    // protect LDS overlay
    unsigned short (*lo4)[64][PAD] = (unsigned short(*)[64][PAD])sm;  // wave-private
#pragma unroll
    for (int mt = 0; mt < 4; ++mt)
#pragma unroll
      for (int nt = 0; nt < 4; ++nt)
#pragma unroll
        for (int r = 0; r < 4; ++r)
          lo4[wid][mt * 16 + quad * 4 + r][nt * 16 + lid] =
            f2bf_rne(acc[mt][nt][r] + bias[mt][r]);
    __builtin_amdgcn_s_waitcnt(0);      // wave-local LDS drain
    unsigned short* base = (unsigned short*)out
      + ((size_t)b * CH + m0 + rw * 64) * SL + l0 + cw * 64;
#pragma unroll
    for (int p = 0; p < 8; ++p) {
      int mr = p * 8 + (lane >> 3), seg = lane & 7;
      *(u16x8*)&base[(size_t)mr * SL + seg * 8] = *(const u16x8*)&lo4[wid][mr][seg * 8];
    }
  } else {
#pragma unroll
    for (int mt = 0; mt < 4; ++mt)
#pragma unroll
      for (int nt = 0; nt < 4; ++nt)
#pragma unroll
        for (int r = 0; r < 4; ++r) {
          int m = m0 + rw * 64 + mt * 16 + quad * 4 + r;
          int l = l0 + cw * 64 + nt * 16 + lid;
          ((float*)out)[((size_t)b * CH + m) * SL + l] = acc[mt][nt][r] + bias[mt][r];
        }
  }
}

extern "C" void kernel_launch(void* const* d_in, const int* in_sizes, int n_in,
                              void* d_out, int out_size, void* d_ws, size_t ws_size,
                              hipStream_t stream) {
  (void)in_sizes; (void)n_in; (void)out_size; (void)ws_size;
  const void* x  = d_in[0];
  const void* wq = d_in[1]; const void* bq = d_in[2];
  const void* wk = d_in[3]; const void* bk = d_in[4];
  const void* wv = d_in[5]; const void* bv = d_in[6];
  const void* wo = d_in[7]; const void* bo = d_in[8];
  const void* ek = d_in[9]; const void* ev = d_in[10];

  const size_t NQ = (size_t)NB * NH * SL * HD;     // 3,145,728 per tensor
  const size_t NX = (size_t)NB * SL * CH;          // 3,145,728
  char* w = (char*)d_ws;
  int*   flag = (int*)w;                 w += 256;
  f16*   wh   = (f16*)w;                 w += 4 * CH * CH * sizeof(f16);   // 1.18 MB
  float* bh   = (float*)w;               w += 4 * CH * sizeof(float);
  f16*   xt   = (f16*)w;                 w += NX * sizeof(f16);
  f16*   Q    = (f16*)w;                 w += NQ * sizeof(f16);
  f16*   K    = (f16*)w;                 w += NQ * sizeof(f16);
  f16*   Vt   = (f16*)w;                 w += NQ * sizeof(f16);
  f16*   R2t  = (f16*)w;                 w += NX * sizeof(f16);

  cvt_k   <<<1345, 256, 0, stream>>>(wq, wk, wv, wo, bq, bk, bv, bo, x, wh, bh, xt, flag);
  qkv_k   <<<dim3(8, 9, NB), 256, 0, stream>>>(wh, bh, xt, Q, K, Vt);
  attn_k  <<<768, 256, 0, stream>>>(Q, K, Vt, ek, ev, R2t, flag);
  out_k   <<<dim3(8, 3, NB), 256, 0, stream>>>(wh, bh, R2t, d_out, flag);
}

// Round 6
// 142.066 us; speedup vs baseline: 1.0382x; 1.0366x over previous
//
#include <hip/hip_runtime.h>
#include <hip/hip_bf16.h>

#define NB 8
#define CH 384
#define SL 1024
#define NH 6
#define HD 64
#define WIN 4
#define LOG2E 1.44269504088896340736f
#define SCALE 0.125f            // 1/sqrt(64)
#define QSCALE (SCALE * LOG2E)  // fold log2(e): attention runs in exp2 domain
#define SCLAMP2 14.4269504f     // 10*log2e; exp2(14.43)=e^10=22026 < fp16 max
#define PAD 72                  // r2 measured-best

typedef _Float16 f16;
typedef f16   f16x8 __attribute__((ext_vector_type(8)));
typedef f16   f16x4 __attribute__((ext_vector_type(4)));
typedef f16   f16x2 __attribute__((ext_vector_type(2)));
typedef float f32x4 __attribute__((ext_vector_type(4)));
typedef unsigned short u16x8 __attribute__((ext_vector_type(8)));
typedef unsigned short u16x4 __attribute__((ext_vector_type(4)));

static __device__ __forceinline__ unsigned short f2bf_rne(float f) {
  unsigned int u = __float_as_uint(f);
  unsigned int r = (u + 0x7fffu + ((u >> 16) & 1u)) >> 16;
  return (unsigned short)r;
}
static __device__ __forceinline__ float bfb(unsigned short u) {   // bf16 bits -> f32
  return __uint_as_float((unsigned int)u << 16);
}
static __device__ __forceinline__ float ldbf(const void* p, size_t i) {
  return bfb(((const unsigned short*)p)[i]);
}
static __device__ __forceinline__ float ldf(const void* p, size_t i) {
  return ((const float*)p)[i];
}
// raw v_exp_f32 (2^x); safe: upstream clamps the high side, low side flushes to 0
static __device__ __forceinline__ float fexp2(float x) {
  return __builtin_amdgcn_exp2f(x);
}
// v_cvt_pkrtz_f16_f32 wrapper: builtin returns __fp16 ext_vector(2); bit-cast
// to our _Float16 vector type (identical layout; r5 compile-error fix).
static __device__ __forceinline__ f16x2 pkrtz(float a, float b) {
  return __builtin_bit_cast(f16x2, __builtin_amdgcn_cvt_pkrtz(a, b));
}

// raw barrier: LDS-visibility only, NO vmcnt drain (loop has no global stores;
// prefetch loads must survive across the barrier — HK T3/T4 pattern).
#define BAR() do {                                            \
    asm volatile("s_waitcnt lgkmcnt(0)" ::: "memory");        \
    __builtin_amdgcn_s_barrier();                             \
    asm volatile("" ::: "memory");                            \
  } while (0)

// ---------------------------------------------------------------------------
// Kc: merged conversions + inline dtype probe (unchanged).
// ---------------------------------------------------------------------------
__global__ __launch_bounds__(256) void cvt_k(
    const void* __restrict__ w0, const void* __restrict__ w1,
    const void* __restrict__ w2, const void* __restrict__ w3,
    const void* __restrict__ b0, const void* __restrict__ b1,
    const void* __restrict__ b2, const void* __restrict__ b3,
    const void* __restrict__ x,
    f16* __restrict__ wh, float* __restrict__ bh, f16* __restrict__ xt,
    int* __restrict__ flag)
{
  __shared__ f16 lt_[64][72];
  __shared__ int sflag;
  const int bx = blockIdx.x, t = threadIdx.x;

  {
    int cnt = 0;
    if (t < 64) {
      const unsigned int* xu = (const unsigned int*)x;
#pragma unroll
      for (int i = 0; i < 4; ++i) {
        unsigned int e = (xu[t * 4 + i] >> 7) & 0xFF;
        if (e >= 110 && e <= 140) ++cnt;
      }
#pragma unroll
      for (int s = 1; s < 64; s <<= 1) cnt += __shfl_xor(cnt, s);
      if (t == 0) sflag = (cnt >= 128) ? 1 : 0;
    }
    __syncthreads();
  }
  const int isbf = sflag;

  if (bx < 576) {                       // 144 blocks per matrix
    int g = bx / 144;
    const void* src = (g == 0) ? w0 : (g == 1) ? w1 : (g == 2) ? w2 : w3;
    size_t idx = (size_t)(bx % 144) * 1024 + t * 4;
    f16* dst = wh + (size_t)g * CH * CH + idx;
    f16x4 o;
    if (!isbf) {
      float4 v = *(const float4*)((const float*)src + idx);
      o[0] = (f16)v.x; o[1] = (f16)v.y; o[2] = (f16)v.z; o[3] = (f16)v.w;
    } else {
      u16x4 v = *(const u16x4*)((const unsigned short*)src + idx);
#pragma unroll
      for (int j = 0; j < 4; ++j) o[j] = (f16)bfb(v[j]);
    }
    *(f16x4*)dst = o;
    return;
  }
  if (bx == 576) {                      // biases + publish flag
    if (t == 0) *flag = isbf;
    for (int e = t; e < 4 * CH; e += 256) {
      int g = e / CH, i = e - g * CH;
      const void* src = (g == 0) ? b0 : (g == 1) ? b1 : (g == 2) ? b2 : b3;
      bh[e] = isbf ? ldbf(src, i) : ldf(src, i);
    }
    return;
  }
  // x transpose: e in 0..767
  const int e  = bx - 577;
  const int l0 = (e & 15) * 64;
  const int c0 = ((e >> 4) % 6) * 64;
  const int b  = e / 96;
  const int row = t >> 4, lseg = t & 15;

  if (!isbf) {
    const float* xf = (const float*)x;
#pragma unroll
    for (int k = 0; k < 4; ++k) {
      int c = c0 + row + 16 * k;
      float4 v = *(const float4*)&xf[((size_t)b * CH + c) * SL + l0 + lseg * 4];
      lt_[lseg * 4 + 0][row + 16 * k] = (f16)v.x;
      lt_[lseg * 4 + 1][row + 16 * k] = (f16)v.y;
      lt_[lseg * 4 + 2][row + 16 * k] = (f16)v.z;
      lt_[lseg * 4 + 3][row + 16 * k] = (f16)v.w;
    }
  } else {
    const unsigned short* xu = (const unsigned short*)x;
#pragma unroll
    for (int k = 0; k < 4; ++k) {
      int c = c0 + row + 16 * k;
      u16x4 v = *(const u16x4*)&xu[((size_t)b * CH + c) * SL + l0 + lseg * 4];
#pragma unroll
      for (int j = 0; j < 4; ++j)
        lt_[lseg * 4 + j][row + 16 * k] = (f16)bfb(v[j]);
    }
  }
  __syncthreads();
  const int l = t >> 2, seg = t & 3;
  f16* dst = &xt[((size_t)b * SL + l0 + l) * CH + c0 + seg * 16];
  *(f16x8*)dst       = *(const f16x8*)&lt_[l][seg * 16];
  *(f16x8*)(dst + 8) = *(const f16x8*)&lt_[l][seg * 16 + 8];
}

// ---------------------------------------------------------------------------
// K1: QKV projection, 128x128-tile fp16 MFMA GEMM (r2 version, pad 72).
// ---------------------------------------------------------------------------
__global__ __launch_bounds__(256) void qkv_k(
    const f16* __restrict__ wh, const float* __restrict__ bh, const f16* __restrict__ xt,
    f16* __restrict__ Q, f16* __restrict__ K, f16* __restrict__ Vt)
{
  __shared__ f16 sm[2][128][PAD];

  const int t   = threadIdx.x;
  const int l0  = blockIdx.x * 128;
  const int mty = blockIdx.y;           // 0..8
  const int b   = blockIdx.z;
  const int wid = t >> 6, lane = t & 63;
  const int quad = lane >> 4, lid = lane & 15;
  const int rw = wid >> 1, cw = wid & 1;

  const int g0   = mty / 3;             // 0=Q, 1=K, 2=V
  const int m128 = (mty % 3) * 128;
  const f16* wg  = wh + (size_t)g0 * CH * CH;

  f32x4 acc[4][4];
#pragma unroll
  for (int mt = 0; mt < 4; ++mt)
#pragma unroll
    for (int nt = 0; nt < 4; ++nt) acc[mt][nt] = (f32x4){0.f, 0.f, 0.f, 0.f};

  for (int c0 = 0; c0 < CH; c0 += 64) {
    __syncthreads();
#pragma unroll
    for (int k = 0; k < 4; ++k) {
      int cidx = t + k * 256;
      int r = cidx >> 3, c8 = (cidx & 7) * 8;
      *(f16x8*)&sm[0][r][c8] = *(const f16x8*)&wg[(size_t)(m128 + r) * CH + c0 + c8];
      *(f16x8*)&sm[1][r][c8] = *(const f16x8*)&xt[((size_t)b * SL + l0 + r) * CH + c0 + c8];
    }
    __syncthreads();
#pragma unroll
    for (int kk = 0; kk < 2; ++kk) {
      f16x8 bf[4];
#pragma unroll
      for (int nt = 0; nt < 4; ++nt)
        bf[nt] = *(const f16x8*)&sm[1][cw * 64 + nt * 16 + lid][kk * 32 + quad * 8];
#pragma unroll
      for (int mt = 0; mt < 4; ++mt) {
        f16x8 af = *(const f16x8*)&sm[0][rw * 64 + mt * 16 + lid][kk * 32 + quad * 8];
#pragma unroll
        for (int nt = 0; nt < 4; ++nt)
          acc[mt][nt] = __builtin_amdgcn_mfma_f32_16x16x32_f16(af, bf[nt], acc[mt][nt], 0, 0, 0);
      }
    }
  }
  __syncthreads();                      // protect LDS overlay

  const int h = (mty % 3) * 2 + rw;
  float bias[4][4];
#pragma unroll
  for (int mt = 0; mt < 4; ++mt)
#pragma unroll
    for (int r = 0; r < 4; ++r)
      bias[mt][r] = bh[g0 * CH + m128 + rw * 64 + mt * 16 + quad * 4 + r];
  const float osc = (g0 == 0) ? QSCALE : 1.0f;

  f16 (*lo4)[64][PAD] = (f16(*)[64][PAD])sm;   // wave-private overlay

  if (g0 < 2) {                         // Q or K: lo[l][d], store (B,H,L,64)
#pragma unroll
    for (int mt = 0; mt < 4; ++mt)
#pragma unroll
      for (int nt = 0; nt < 4; ++nt) {
        f16x4 vv;
#pragma unroll
        for (int r = 0; r < 4; ++r)
          vv[r] = (f16)((acc[mt][nt][r] + bias[mt][r]) * osc);
        *(f16x4*)&lo4[wid][nt * 16 + lid][mt * 16 + quad * 4] = vv;
      }
    __builtin_amdgcn_s_waitcnt(0);
    f16* base = ((g0 == 0) ? Q : K) + ((size_t)(b * NH + h) * SL + l0 + cw * 64) * HD;
#pragma unroll
    for (int p = 0; p < 8; ++p) {
      int lr = p * 8 + (lane >> 3), seg = lane & 7;
      *(f16x8*)&base[(size_t)lr * HD + seg * 8] = *(const f16x8*)&lo4[wid][lr][seg * 8];
    }
  } else {                              // V: lo[d][l], store (B,H,64,L)
#pragma unroll
    for (int mt = 0; mt < 4; ++mt)
#pragma unroll
      for (int nt = 0; nt < 4; ++nt)
#pragma unroll
        for (int r = 0; r < 4; ++r)
          lo4[wid][mt * 16 + quad * 4 + r][nt * 16 + lid] =
            (f16)(acc[mt][nt][r] + bias[mt][r]);
    __builtin_amdgcn_s_waitcnt(0);
    f16* base = Vt + ((size_t)(b * NH + h) * HD) * SL + l0 + cw * 64;
#pragma unroll
    for (int p = 0; p < 8; ++p) {
      int dr = p * 8 + (lane >> 3), seg = lane & 7;
      *(f16x8*)&base[(size_t)dr * SL + seg * 8] = *(const f16x8*)&lo4[wid][dr][seg * 8];
    }
  }
}

// ---------------------------------------------------------------------------
// K2: MFMA flash attention — round-16 (r5 recompile): VALU-issue reduction.
//  (1) manual 2x unroll w/ compile-time buffer index (inlined lambda): all 16
//      LDS ops fold to base+immediate offset, no runtime ib address math;
//      global prefetch via 4 running pointers (8 adds / 2 tiles).
//  (2) v_cvt_pkrtz_f16_f32 packs P pairs (16 cvt+pack -> 8 pkrtz). Safe:
//      l sums the SAME rounded pb values, so P/l bias cancels first-order.
// Quadrant ownership + raw barriers kept from r15 (correct, fewer LDS ops).
// ---------------------------------------------------------------------------
__global__ __launch_bounds__(256, 3) void attn_k(
    const f16* __restrict__ Qs, const f16* __restrict__ Kg, const f16* __restrict__ Vtg,
    const void* __restrict__ embk, const void* __restrict__ embv,
    f16* __restrict__ R2t, const int* __restrict__ flag)
{
  __shared__ f16 bufall[4][64][PAD];    // [0..1] = K dbuf, [2..3] = V dbuf
  __shared__ float lbias[64][12];
  __shared__ float lsb[64][12];
  __shared__ float lev[9][64];
  __shared__ float ll64[64];
  __shared__ float lred[4][2][16];

  const int isbf = *flag;
  const int t    = threadIdx.x;

  const int id   = blockIdx.x;
  const int xcd  = id & 7;
  const int kk   = id >> 3;
  const int pair = (kk % 6) * 8 + xcd;
  const int i0   = (kk / 6) * 64;
  const int b    = pair / NH;
  const int h    = pair % NH;

  const int wid  = t >> 6;
  const int lane = t & 63;
  const int quad = lane >> 4;
  const int lid  = lane & 15;
  const int ih   = wid >> 1;            // i-half owned
  const int jh   = wid & 1;             // j-half owned
  const int irow = 16 * wid + lid;      // epilogue i-row (post-reduction)

  const f16* Qb = Qs  + ((size_t)(b * NH + h) * SL) * HD;
  const f16* Kb = Kg  + ((size_t)(b * NH + h) * SL) * HD;
  const f16* Vb = Vtg + ((size_t)(b * NH + h) * HD) * SL;

  f16 (*bufk)[64][PAD] = &bufall[0];
  f16 (*bufv)[64][PAD] = &bufall[2];
  f16 (* const lq)[PAD] = bufall[0];    // prologue overlay
  f16 (* const lo)[PAD] = bufall[0];    // epilogue overlay

  const int r_0 = t >> 3, c8 = (t & 7) * 8;
  const int r_1 = (t + 256) >> 3;

  // stage Q tile into bufall[0]
#pragma unroll
  for (int k = 0; k < 2; ++k) {
    int c = t + k * 256, r = c >> 3, cc8 = (c & 7) * 8;
    *(f16x8*)&lq[r][cc8] = *(const f16x8*)&Qb[(size_t)(i0 + r) * HD + cc8];
  }
  // prefetch tile 0 via running pointers (advanced by constant per tile)
  const f16* pKa = Kb + (size_t)r_0 * HD + c8;
  const f16* pKb = Kb + (size_t)r_1 * HD + c8;
  const f16* pVa = Vb + (size_t)r_0 * SL + c8;
  const f16* pVb = Vb + (size_t)r_1 * SL + c8;
  f16x8 pk0 = *(const f16x8*)pKa;
  f16x8 pk1 = *(const f16x8*)pKb;
  f16x8 pv0 = *(const f16x8*)pVa;
  f16x8 pv1 = *(const f16x8*)pVb;

  for (int e = t; e < 576; e += 256) {
    int p = e >> 6, c = e & 63;
    lev[p][c] = isbf ? ldbf(embv, (size_t)h * 576 + e) : ldf(embv, (size_t)h * 576 + e);
  }
  for (int e = t; e < 768; e += 256) ((float*)lsb)[e] = -1e30f;
  BAR();                                // P1: lq/lev/lsb visible (no vmem drain)

  // Q fragments for the wave's i-half: nt in {0,1} -> i-strip ih*32 + nt*16
  f16x8 qn0[2], qn1[2];
#pragma unroll
  for (int nt = 0; nt < 2; ++nt) {
    qn0[nt] = *(const f16x8*)&lq[ih * 32 + nt * 16 + lid][quad * 8];
    qn1[nt] = *(const f16x8*)&lq[ih * 32 + nt * 16 + lid][32 + quad * 8];
  }

  // band bias via MFMA (strip wid = (ih, nt=jh)): table lbias[i][d], i-indexed
  {
    int row = h * 9 + (lid < 9 ? lid : 0);
    f16x8 ekf0, ekf1;
    if (!isbf) {
      const float* ek = (const float*)embk;
#pragma unroll
      for (int e = 0; e < 8; ++e) {
        ekf0[e] = (f16)ek[(size_t)row * HD + quad * 8 + e];
        ekf1[e] = (f16)ek[(size_t)row * HD + 32 + quad * 8 + e];
      }
    } else {
      const unsigned short* ek = (const unsigned short*)embk;
      u16x8 v0 = *(const u16x8*)&ek[(size_t)row * HD + quad * 8];
      u16x8 v1 = *(const u16x8*)&ek[(size_t)row * HD + 32 + quad * 8];
#pragma unroll
      for (int e = 0; e < 8; ++e) { ekf0[e] = (f16)bfb(v0[e]); ekf1[e] = (f16)bfb(v1[e]); }
    }
    f32x4 bd = (f32x4){0.f, 0.f, 0.f, 0.f};
    bd = __builtin_amdgcn_mfma_f32_16x16x32_f16(ekf0, qn0[jh], bd, 0, 0, 0);
    bd = __builtin_amdgcn_mfma_f32_16x16x32_f16(ekf1, qn1[jh], bd, 0, 0, 0);
#pragma unroll
    for (int r = 0; r < 4; ++r) {
      int p = quad * 4 + r;
      if (p < 9) lbias[irow][p] = bd[r];
    }
  }
  BAR();                                // P2: Q frags read; bufall[0] reusable

  const f16x4 ones4 = {(f16)1.f, (f16)1.f, (f16)1.f, (f16)1.f};

  f32x4 Op[2][4];                       // [nt][dt] partial O (j in jh-half)
  f32x4 Os[2];                          // [nt] partial l
#pragma unroll
  for (int nt = 0; nt < 2; ++nt) {
    Os[nt] = (f32x4){0.f, 0.f, 0.f, 0.f};
#pragma unroll
    for (int dt = 0; dt < 4; ++dt) Op[nt][dt] = (f32x4){0.f, 0.f, 0.f, 0.f};
  }

  // one j-tile; IB must be a literal so every LDS address folds to base+imm
  auto tile = [&](const int IB, const int j0, const bool last) __attribute__((always_inline)) {
    // drain prefetch regs into LDS buf[IB] (write BEFORE barrier)
    *(f16x8*)&bufk[IB][r_0][c8] = pk0;
    *(f16x8*)&bufk[IB][r_1][c8] = pk1;
    *(f16x8*)&bufv[IB][r_0][c8] = pv0;
    *(f16x8*)&bufv[IB][r_1][c8] = pv1;
    BAR();                              // LDS-visibility only; vmem stays in flight

    if (!last) {
      pKa += 64 * HD; pKb += 64 * HD; pVa += 64; pVb += 64;
      pk0 = *(const f16x8*)pKa;
      pk1 = *(const f16x8*)pKb;
      pv0 = *(const f16x8*)pVa;
      pv1 = *(const f16x8*)pVb;
    }

    // K fragments: only the wave's jh half-strip
    f16x8 a00 = *(const f16x8*)&bufk[IB][jh * 32 + lid][quad * 8];
    f16x8 a10 = *(const f16x8*)&bufk[IB][jh * 32 + lid][32 + quad * 8];
    f16x8 a01 = *(const f16x8*)&bufk[IB][jh * 32 + 16 + lid][quad * 8];
    f16x8 a11 = *(const f16x8*)&bufk[IB][jh * 32 + 16 + lid][32 + quad * 8];

    // S^T quadrant (scores in log2 domain): sc[jt][nt]
    f32x4 sc[2][2];
#pragma unroll
    for (int nt = 0; nt < 2; ++nt) {
      f32x4 z = (f32x4){0.f, 0.f, 0.f, 0.f};
      sc[0][nt] = __builtin_amdgcn_mfma_f32_16x16x32_f16(a00, qn0[nt], z, 0, 0, 0);
      sc[0][nt] = __builtin_amdgcn_mfma_f32_16x16x32_f16(a10, qn1[nt], sc[0][nt], 0, 0, 0);
      sc[1][nt] = __builtin_amdgcn_mfma_f32_16x16x32_f16(a01, qn0[nt], z, 0, 0, 0);
      sc[1][nt] = __builtin_amdgcn_mfma_f32_16x16x32_f16(a11, qn1[nt], sc[1][nt], 0, 0, 0);
    }

    if (j0 - i0 <= 64 && i0 - j0 <= 64) {
#pragma unroll
      for (int jt = 0; jt < 2; ++jt)
#pragma unroll
        for (int nt = 0; nt < 2; ++nt)
#pragma unroll
          for (int r = 0; r < 4; ++r) {
            int jl = jh * 32 + jt * 16 + quad * 4 + r;
            int il = ih * 32 + nt * 16 + lid;
            int d = (j0 + jl) - (i0 + il) + WIN;
            if (d >= 0 && d <= 2 * WIN) {
              float s = sc[jt][nt][r] + lbias[il][d];
              sc[jt][nt][r] = s;
              lsb[il][d] = s;
            }
          }
    }

    f16x4 pb[2][2];
#pragma unroll
    for (int jt = 0; jt < 2; ++jt)
#pragma unroll
      for (int nt = 0; nt < 2; ++nt) {
        float e0 = fexp2(fminf(sc[jt][nt][0], SCLAMP2));
        float e1 = fexp2(fminf(sc[jt][nt][1], SCLAMP2));
        float e2 = fexp2(fminf(sc[jt][nt][2], SCLAMP2));
        float e3 = fexp2(fminf(sc[jt][nt][3], SCLAMP2));
        f16x2 p01 = pkrtz(e0, e1);
        f16x2 p23 = pkrtz(e2, e3);
        pb[jt][nt] = __builtin_shufflevector(p01, p23, 0, 1, 2, 3);
      }

#pragma unroll
    for (int nt = 0; nt < 2; ++nt) {
      Os[nt] = __builtin_amdgcn_mfma_f32_16x16x16f16(ones4, pb[0][nt], Os[nt], 0, 0, 0);
      Os[nt] = __builtin_amdgcn_mfma_f32_16x16x16f16(ones4, pb[1][nt], Os[nt], 0, 0, 0);
    }

    // PV: V k-slices for the jh half only (b64 reads, straight layout)
#pragma unroll
    for (int dt = 0; dt < 4; ++dt) {
      f16x4 vf0 = *(const f16x4*)&bufv[IB][dt * 16 + lid][jh * 32 + quad * 4];
      f16x4 vf1 = *(const f16x4*)&bufv[IB][dt * 16 + lid][jh * 32 + 16 + quad * 4];
#pragma unroll
      for (int nt = 0; nt < 2; ++nt) {
        Op[nt][dt] = __builtin_amdgcn_mfma_f32_16x16x16f16(vf0, pb[0][nt], Op[nt][dt], 0, 0, 0);
        Op[nt][dt] = __builtin_amdgcn_mfma_f32_16x16x16f16(vf1, pb[1][nt], Op[nt][dt], 0, 0, 0);
      }
    }
  };

  // 16 tiles = 8 unrolled pairs; IB literal 0/1 per copy
  for (int j0 = 0; j0 < SL; j0 += 128) {
    tile(0, j0, false);
    tile(1, j0 + 64, j0 + 128 >= SL);
  }

  // ---- cross-wave reduction: strip s gets contribs from waves (s>>1)*2(+1) ----
  __syncthreads();                      // all bufall reads done
  float* red = (float*)bufall;          // 32 slots x 1KB = 32KB (fits 36.8KB)
#pragma unroll
  for (int nt = 0; nt < 2; ++nt)
#pragma unroll
    for (int dt = 0; dt < 4; ++dt)
      *(f32x4*)&red[(((wid * 2 + nt) * 4 + dt) * 64 + lane) * 4] = Op[nt][dt];
  if (quad == 0) {
    lred[wid][0][lid] = Os[0][0];       // l rows are identical across m: take r=0
    lred[wid][1][lid] = Os[1][0];
  }
  __syncthreads();

  const int u0w = (wid >> 1) * 2, u1w = u0w + 1, ntw = wid & 1;
  f32x4 O[4];
#pragma unroll
  for (int dt = 0; dt < 4; ++dt) {
    f32x4 xA = *(const f32x4*)&red[(((u0w * 2 + ntw) * 4 + dt) * 64 + lane) * 4];
    f32x4 xB = *(const f32x4*)&red[(((u1w * 2 + ntw) * 4 + dt) * 64 + lane) * 4];
    O[dt] = xA + xB;
  }
  const float lsum = lred[u0w][ntw][lid] + lred[u1w][ntw][lid];
  if (quad == 0) ll64[irow] = lsum;
  __syncthreads();                      // red reads done; ll64 visible

  for (int e = t; e < 576; e += 256) {
    int r = e / 9, p = e - r * 9;
    lsb[r][p] = fexp2(fminf(lsb[r][p], SCLAMP2)) * __builtin_amdgcn_rcpf(ll64[r]);
  }
  __syncthreads();

  {
    const float rl = __builtin_amdgcn_rcpf(lsum);
    float lp[9];
#pragma unroll
    for (int p = 0; p < 9; ++p) lp[p] = lsb[irow][p];
    float val[4][4];
#pragma unroll
    for (int dt = 0; dt < 4; ++dt)
#pragma unroll
      for (int r = 0; r < 4; ++r) val[dt][r] = O[dt][r] * rl;
#pragma unroll
    for (int p = 0; p < 9; ++p)
#pragma unroll
      for (int dt = 0; dt < 4; ++dt)
#pragma unroll
        for (int r = 0; r < 4; ++r)
          val[dt][r] += lp[p] * lev[p][dt * 16 + quad * 4 + r];
#pragma unroll
    for (int dt = 0; dt < 4; ++dt) {
      f16x4 vv;
#pragma unroll
      for (int r = 0; r < 4; ++r) vv[r] = (f16)val[dt][r];
      *(f16x4*)&lo[irow][dt * 16 + quad * 4] = vv;
    }
  }
  __syncthreads();

  {
    const int l = t >> 2, seg = t & 3;
    f16* dst = &R2t[((size_t)b * SL + i0 + l) * CH + h * 64 + seg * 16];
    *(f16x8*)dst       = *(const f16x8*)&lo[l][seg * 16];
    *(f16x8*)(dst + 8) = *(const f16x8*)&lo[l][seg * 16 + 8];
  }
}

// ---------------------------------------------------------------------------
// K3: output projection, 128x128-tile fp16 MFMA GEMM (r2 version, pad 72).
// ---------------------------------------------------------------------------
__global__ __launch_bounds__(256) void out_k(
    const f16* __restrict__ wh, const float* __restrict__ bh, const f16* __restrict__ R2t,
    void* __restrict__ out, const int* __restrict__ flag)
{
  __shared__ f16 sm[2][128][PAD];

  const int isbf = *flag;
  const int t   = threadIdx.x;
  const int l0  = blockIdx.x * 128;
  const int m0  = blockIdx.y * 128;
  const int b   = blockIdx.z;
  const int wid = t >> 6, lane = t & 63;
  const int quad = lane >> 4, lid = lane & 15;
  const int rw = wid >> 1, cw = wid & 1;

  const f16* wg = wh + (size_t)3 * CH * CH;

  f32x4 acc[4][4];
#pragma unroll
  for (int mt = 0; mt < 4; ++mt)
#pragma unroll
    for (int nt = 0; nt < 4; ++nt) acc[mt][nt] = (f32x4){0.f, 0.f, 0.f, 0.f};

  for (int c0 = 0; c0 < CH; c0 += 64) {
    __syncthreads();
#pragma unroll
    for (int k = 0; k < 4; ++k) {
      int cidx = t + k * 256;
      int r = cidx >> 3, c8 = (cidx & 7) * 8;
      *(f16x8*)&sm[0][r][c8] = *(const f16x8*)&wg[(size_t)(m0 + r) * CH + c0 + c8];
      *(f16x8*)&sm[1][r][c8] = *(const f16x8*)&R2t[((size_t)b * SL + l0 + r) * CH + c0 + c8];
    }
    __syncthreads();
#pragma unroll
    for (int kk = 0; kk < 2; ++kk) {
      f16x8 bf[4];
#pragma unroll
      for (int nt = 0; nt < 4; ++nt)
        bf[nt] = *(const f16x8*)&sm[1][cw * 64 + nt * 16 + lid][kk * 32 + quad * 8];
#pragma unroll
      for (int mt = 0; mt < 4; ++mt) {
        f16x8 af = *(const f16x8*)&sm[0][rw * 64 + mt * 16 + lid][kk * 32 + quad * 8];
#pragma unroll
        for (int nt = 0; nt < 4; ++nt)
          acc[mt][nt] = __builtin_amdgcn_mfma_f32_16x16x32_f16(af, bf[nt], acc[mt][nt], 0, 0, 0);
      }
    }
  }

  float bias[4][4];
#pragma unroll
  for (int mt = 0; mt < 4; ++mt)
#pragma unroll
    for (int r = 0; r < 4; ++r)
      bias[mt][r] = bh[3 * CH + m0 + rw * 64 + mt * 16 + quad * 4 + r];

  if (isbf) {
    __syncthreads();                    // protect LDS overlay
    unsigned short (*lo4)[64][PAD] = (unsigned short(*)[64][PAD])sm;  // wave-private
#pragma unroll
    for (int mt = 0; mt < 4; ++mt)
#pragma unroll
      for (int nt = 0; nt < 4; ++nt)
#pragma unroll
        for (int r = 0; r < 4; ++r)
          lo4[wid][mt * 16 + quad * 4 + r][nt * 16 + lid] =
            f2bf_rne(acc[mt][nt][r] + bias[mt][r]);
    __builtin_amdgcn_s_waitcnt(0);      // wave-local LDS drain
    unsigned short* base = (unsigned short*)out
      + ((size_t)b * CH + m0 + rw * 64) * SL + l0 + cw * 64;
#pragma unroll
    for (int p = 0; p < 8; ++p) {
      int mr = p * 8 + (lane >> 3), seg = lane & 7;
      *(u16x8*)&base[(size_t)mr * SL + seg * 8] = *(const u16x8*)&lo4[wid][mr][seg * 8];
    }
  } else {
#pragma unroll
    for (int mt = 0; mt < 4; ++mt)
#pragma unroll
      for (int nt = 0; nt < 4; ++nt)
#pragma unroll
        for (int r = 0; r < 4; ++r) {
          int m = m0 + rw * 64 + mt * 16 + quad * 4 + r;
          int l = l0 + cw * 64 + nt * 16 + lid;
          ((float*)out)[((size_t)b * CH + m) * SL + l] = acc[mt][nt][r] + bias[mt][r];
        }
  }
}

extern "C" void kernel_launch(void* const* d_in, const int* in_sizes, int n_in,
                              void* d_out, int out_size, void* d_ws, size_t ws_size,
                              hipStream_t stream) {
  (void)in_sizes; (void)n_in; (void)out_size; (void)ws_size;
  const void* x  = d_in[0];
  const void* wq = d_in[1]; const void* bq = d_in[2];
  const void* wk = d_in[3]; const void* bk = d_in[4];
  const void* wv = d_in[5]; const void* bv = d_in[6];
  const void* wo = d_in[7]; const void* bo = d_in[8];
  const void* ek = d_in[9]; const void* ev = d_in[10];

  const size_t NQ = (size_t)NB * NH * SL * HD;     // 3,145,728 per tensor
  const size_t NX = (size_t)NB * SL * CH;          // 3,145,728
  char* w = (char*)d_ws;
  int*   flag = (int*)w;                 w += 256;
  f16*   wh   = (f16*)w;                 w += 4 * CH * CH * sizeof(f16);   // 1.18 MB
  float* bh   = (float*)w;               w += 4 * CH * sizeof(float);
  f16*   xt   = (f16*)w;                 w += NX * sizeof(f16);
  f16*   Q    = (f16*)w;                 w += NQ * sizeof(f16);
  f16*   K    = (f16*)w;                 w += NQ * sizeof(f16);
  f16*   Vt   = (f16*)w;                 w += NQ * sizeof(f16);
  f16*   R2t  = (f16*)w;                 w += NX * sizeof(f16);

  cvt_k   <<<1345, 256, 0, stream>>>(wq, wk, wv, wo, bq, bk, bv, bo, x, wh, bh, xt, flag);
  qkv_k   <<<dim3(8, 9, NB), 256, 0, stream>>>(wh, bh, xt, Q, K, Vt);
  attn_k  <<<768, 256, 0, stream>>>(Q, K, Vt, ek, ev, R2t, flag);
  out_k   <<<dim3(8, 3, NB), 256, 0, stream>>>(wh, bh, R2t, d_out, flag);
}